// Round 2
// baseline (249.680 us; speedup 1.0000x reference)
//
#include <hip/hip_runtime.h>

#define B_  4
#define N_  4096   // H*W
#define C_  256
#define D_  32

typedef __attribute__((ext_vector_type(8))) short bf8;    // 8 bf16 (4 VGPRs)
typedef __attribute__((ext_vector_type(4))) float f4;     // 16x16 MFMA C/D frag
typedef __attribute__((ext_vector_type(16))) float f16v;  // 32x32 MFMA C/D frag

__device__ __forceinline__ unsigned short bft(float f) {
    unsigned u = __builtin_bit_cast(unsigned, f);
    return (unsigned short)((u + 0x8000u) >> 16);
}
// pack two floats to bf16x2 (a->low, b->high), round-half-up, 3 VALU ops
__device__ __forceinline__ unsigned pk2(float a, float b) {
    unsigned ua = __builtin_bit_cast(unsigned, a) + 0x8000u;
    unsigned ub = __builtin_bit_cast(unsigned, b) + 0x8000u;
    return __builtin_amdgcn_perm(ub, ua, 0x07060302u);  // bytes {b3,b2,a3,a2}
}

// ---------------------------------------------------------------------------
// prep: weights -> bf16. Wqkb[64][256] = Wq rows 0-31, Wk rows 32-63.
// ---------------------------------------------------------------------------
__global__ __launch_bounds__(256) void prep(
    const float* __restrict__ Wq, const float* __restrict__ Wk,
    const float* __restrict__ Wv,
    unsigned short* __restrict__ Wqkb, unsigned short* __restrict__ Wvb)
{
    int i = blockIdx.x * 256 + threadIdx.x;
    if (i < 8192)       Wqkb[i] = bft(Wq[i]);
    else if (i < 16384) Wqkb[i] = bft(Wk[i - 8192]);
    Wvb[i] = bft(Wv[i]);
}

// ---------------------------------------------------------------------------
// qkv: MFMA projections, coalesced staging. grid(128,4), 256 thr.
// q is pre-scaled by log2(e) so attn can use raw v_exp_f32 (2^x).
// Outputs: qb,kb [B][N][32] bf16 ; vb [B][C][N] bf16.
// ---------------------------------------------------------------------------
__global__ __launch_bounds__(256) void qkv(
    const float* __restrict__ x,
    const unsigned short* __restrict__ Wqkb, const unsigned short* __restrict__ Wvb,
    const float* __restrict__ bq, const float* __restrict__ bk,
    const float* __restrict__ bv,
    unsigned short* __restrict__ qb, unsigned short* __restrict__ kb,
    unsigned short* __restrict__ vb)
{
    const int b = blockIdx.y, n0 = blockIdx.x * 32;
    const int t = threadIdx.x;
    const int lane = t & 63, w = t >> 6, c15 = lane & 15, g = lane >> 4;

    __shared__ __align__(16) unsigned short xs[32][264];

    // coalesced stage + transpose: 8 lanes cover one 128-B row segment
    {
        const int r = t >> 3, cg = t & 7;
        #pragma unroll
        for (int it = 0; it < 8; ++it) {
            int c = r + 32 * it;
            float4 v = *(const float4*)(x + ((size_t)(b * C_ + c)) * N_ + n0 + cg * 4);
            xs[cg * 4 + 0][c] = bft(v.x);
            xs[cg * 4 + 1][c] = bft(v.y);
            xs[cg * 4 + 2][c] = bft(v.z);
            xs[cg * 4 + 3][c] = bft(v.w);
        }
    }
    __syncthreads();

    f4 qkacc[2]; f4 vacc[2][4];
    const f4 fz = {0.f, 0.f, 0.f, 0.f};
    qkacc[0] = fz; qkacc[1] = fz;
    #pragma unroll
    for (int nt = 0; nt < 2; ++nt)
        #pragma unroll
        for (int ct = 0; ct < 4; ++ct) vacc[nt][ct] = fz;

    const unsigned short* wqk = Wqkb + (w * 16 + c15) * C_ + g * 8;
    const unsigned short* wv0 = Wvb + (w * 64 + c15) * C_ + g * 8;
    const unsigned short* xsp = &xs[c15][g * 8];

    #pragma unroll
    for (int ks = 0; ks < 8; ++ks) {
        bf8 xf0 = *(const bf8*)(xsp + ks * 32);
        bf8 xf1 = *(const bf8*)(xsp + 16 * 264 + ks * 32);
        bf8 af  = *(const bf8*)(wqk + ks * 32);
        qkacc[0] = __builtin_amdgcn_mfma_f32_16x16x32_bf16(af, xf0, qkacc[0], 0, 0, 0);
        qkacc[1] = __builtin_amdgcn_mfma_f32_16x16x32_bf16(af, xf1, qkacc[1], 0, 0, 0);
        #pragma unroll
        for (int ct = 0; ct < 4; ++ct) {
            bf8 bfv = *(const bf8*)(wv0 + ct * 16 * C_ + ks * 32);
            vacc[0][ct] = __builtin_amdgcn_mfma_f32_16x16x32_bf16(xf0, bfv, vacc[0][ct], 0, 0, 0);
            vacc[1][ct] = __builtin_amdgcn_mfma_f32_16x16x32_bf16(xf1, bfv, vacc[1][ct], 0, 0, 0);
        }
    }

    // epilogue q/k (q scaled by log2e for exp2-softmax)
    {
        float4 bias = (w < 2) ? *(const float4*)(bq + (w & 1) * 16 + 4 * g)
                              : *(const float4*)(bk + (w & 1) * 16 + 4 * g);
        float sc = (w < 2) ? 1.44269504f : 1.0f;
        unsigned short* base = (w < 2) ? qb : kb;
        int d0 = (w & 1) * 16 + 4 * g;
        #pragma unroll
        for (int nt = 0; nt < 2; ++nt) {
            int n = n0 + nt * 16 + c15;
            f4 a = qkacc[nt];
            uint2 pk;
            pk.x = pk2((a.x + bias.x) * sc, (a.y + bias.y) * sc);
            pk.y = pk2((a.z + bias.z) * sc, (a.w + bias.w) * sc);
            *(uint2*)(base + ((size_t)(b * N_ + n)) * D_ + d0) = pk;
        }
    }
    // epilogue v
    #pragma unroll
    for (int ct = 0; ct < 4; ++ct) {
        int cout = w * 64 + ct * 16 + c15;
        float bvv = bv[cout];
        #pragma unroll
        for (int nt = 0; nt < 2; ++nt) {
            f4 a = vacc[nt][ct];
            uint2 pk;
            pk.x = pk2(a.x + bvv, a.y + bvv);
            pk.y = pk2(a.z + bvv, a.w + bvv);
            *(uint2*)(vb + ((size_t)(b * C_ + cout)) * (size_t)N_ + n0 + nt * 16 + 4 * g) = pk;
        }
    }
}

// ---------------------------------------------------------------------------
// attn v3: barrier-free flash attention, fully wave-independent main loop.
// 32x32x16 MFMAs; P stays in registers (half-wave shfl_xor exchange maps the
// S^T fragment layout onto the PV A-operand layout). No LDS, no barrier, no
// bank conflicts in the loop. Wave = (b, 64-m pair, 128-c half, 1024-n
// quarter): 512 blocks x 4 waves = 2 blocks/CU, 8 waves/CU, free drift ->
// MFMA/VALU/trans overlap across waves. n-quarter partials combined once at
// the end through LDS ds_add_f32. bid&7 = (b, c-half) pins each XCD's L2 to
// its 1 MB V-slice.
// Frag layouts (32x32x16): A: lane(r=l&31, h=l>>5) holds k=8h+0..7;
// B: lane(c=l&31, h) holds k=8h+0..7; C/D: col=l&31, row=(reg&3)+8(reg>>2)+4h.
// ---------------------------------------------------------------------------
__global__ __launch_bounds__(256, 2) void attn(
    const unsigned short* __restrict__ qb, const unsigned short* __restrict__ kb,
    const unsigned short* __restrict__ vb, const float* __restrict__ x,
    const float* __restrict__ gamma, float* __restrict__ out)
{
    const int bid = blockIdx.x;
    const int b = (bid & 7) >> 1, c0 = (bid & 1) * 128, m0 = (bid >> 3) * 64;
    const int t = threadIdx.x;
    const int lane = t & 63, w = t >> 6;
    const int cl = lane & 31;
    const int h = lane >> 5;
    const bool hb = (h != 0);

    __shared__ float Osum[64][129];   // +1 pad: conflict-free col-walk reads
    __shared__ float l_tot[64];

    // zero accum LDS (one-time)
    for (int i = t; i < 64 * 129; i += 256) (&Osum[0][0])[i] = 0.f;
    if (t < 64) l_tot[t] = 0.f;
    __syncthreads();

    const unsigned short* qB = qb + (size_t)b * N_ * 32;
    const unsigned short* kB = kb + (size_t)b * N_ * 32;
    const unsigned short* vB = vb + ((size_t)(b * C_ + c0)) * (size_t)N_;

    // Q-frags (hoisted): B-operand of S^T mfma: lane(m=cl,h) holds d=kh*16+8h..
    bf8 qf[2][2];
    #pragma unroll
    for (int mt = 0; mt < 2; ++mt)
        #pragma unroll
        for (int kh = 0; kh < 2; ++kh)
            qf[mt][kh] = *(const bf8*)(qB + (size_t)(m0 + mt * 32 + cl) * 32 + kh * 16 + 8 * h);

    f16v acc[2][4];   // [m-tile][c-tile] : 128 VGPR
    #pragma unroll
    for (int mt = 0; mt < 2; ++mt)
        #pragma unroll
        for (int ct = 0; ct < 4; ++ct) acc[mt][ct] = (f16v)0.f;
    float lr[2] = {0.f, 0.f};

    int n0 = w * 1024;             // this wave's n-quarter
    const int nEnd = n0 + 1024;
    bf8 kfc[2], kfn[2];            // K register double-buffer
    kfc[0] = *(const bf8*)(kB + (size_t)(n0 + cl) * 32 + 8 * h);
    kfc[1] = *(const bf8*)(kB + (size_t)(n0 + cl) * 32 + 16 + 8 * h);

    for (; n0 < nEnd; n0 += 32) {
        // V loads issued early; first use is ~produce+exp later
        bf8 vf[4][2];
        #pragma unroll
        for (int ct = 0; ct < 4; ++ct)
            #pragma unroll
            for (int nh = 0; nh < 2; ++nh)
                vf[ct][nh] = *(const bf8*)(vB + (size_t)(ct * 32 + cl) * N_
                                           + n0 + nh * 16 + 8 * h);
        // next-step K prefetch (latency hidden under produce/exp/PV)
        {
            int n1 = n0 + 32; n1 = (n1 < nEnd) ? n1 : (nEnd - 32);
            kfn[0] = *(const bf8*)(kB + (size_t)(n1 + cl) * 32 + 8 * h);
            kfn[1] = *(const bf8*)(kB + (size_t)(n1 + cl) * 32 + 16 + 8 * h);
        }
        // produce S^T = K.Q^T (lane col = m), exp2, pack to bf16 words
        // Wm[mt][2q+s]: n = 8q + 4h + 2s + {0,1} for lane-half h
        unsigned Wm[2][8];
        #pragma unroll
        for (int mt = 0; mt < 2; ++mt) {
            f16v s = __builtin_amdgcn_mfma_f32_32x32x16_bf16(kfc[0], qf[mt][0], (f16v)0.f, 0, 0, 0);
            s = __builtin_amdgcn_mfma_f32_32x32x16_bf16(kfc[1], qf[mt][1], s, 0, 0, 0);
            float ls = 0.f;
            #pragma unroll
            for (int q = 0; q < 4; ++q) {
                float p0 = __builtin_amdgcn_exp2f(s[4 * q + 0]);
                float p1 = __builtin_amdgcn_exp2f(s[4 * q + 1]);
                float p2 = __builtin_amdgcn_exp2f(s[4 * q + 2]);
                float p3 = __builtin_amdgcn_exp2f(s[4 * q + 3]);
                ls += (p0 + p1) + (p2 + p3);
                Wm[mt][2 * q + 0] = pk2(p0, p1);
                Wm[mt][2 * q + 1] = pk2(p2, p3);
            }
            lr[mt] += ls;
        }
        kfc[0] = kfn[0]; kfc[1] = kfn[1];
        // PV: build natural-k A-frags via half-wave exchange, accumulate O
        #pragma unroll
        for (int mt = 0; mt < 2; ++mt)
            #pragma unroll
            for (int nh = 0; nh < 2; ++nh) {
                unsigned w0a = Wm[mt][4 * nh + 0], w0b = Wm[mt][4 * nh + 1];
                unsigned w1a = Wm[mt][4 * nh + 2], w1b = Wm[mt][4 * nh + 3];
                unsigned s0a = (unsigned)__shfl_xor((int)w0a, 32);
                unsigned s0b = (unsigned)__shfl_xor((int)w0b, 32);
                unsigned s1a = (unsigned)__shfl_xor((int)w1a, 32);
                unsigned s1b = (unsigned)__shfl_xor((int)w1b, 32);
                uint4 z;   // lane-half h needs n-local 8h..8h+7
                z.x = hb ? s1a : w0a;
                z.y = hb ? s1b : w0b;
                z.z = hb ? w1a : s0a;
                z.w = hb ? w1b : s0b;
                bf8 pa = __builtin_bit_cast(bf8, z);
                #pragma unroll
                for (int ct = 0; ct < 4; ++ct)
                    acc[mt][ct] = __builtin_amdgcn_mfma_f32_32x32x16_bf16(pa, vf[ct][nh], acc[mt][ct], 0, 0, 0);
            }
    }

    // one-time combine of the 4 n-quarter partials (LDS float atomics)
    #pragma unroll
    for (int mt = 0; mt < 2; ++mt) {
        atomicAdd(&l_tot[mt * 32 + cl], lr[mt]);
        #pragma unroll
        for (int ct = 0; ct < 4; ++ct) {
            f16v a = acc[mt][ct];
            #pragma unroll
            for (int q = 0; q < 4; ++q)
                #pragma unroll
                for (int r = 0; r < 4; ++r)
                    atomicAdd(&Osum[mt * 32 + 8 * q + 4 * h + r][ct * 32 + cl], a[4 * q + r]);
        }
    }
    __syncthreads();

    // finalize: wave -> (mt = w>>1, 64-c half = w&1); lane: m = mt*32+cl,
    // lane-half picks 32-c; writes 128-B coalesced runs along m.
    {
        const float g0 = gamma[0];
        const int mtF = w >> 1, cq = w & 1;
        const int m = mtF * 32 + cl;
        const float osc = g0 * (1.0f / l_tot[m]);
        const int cbase = cq * 64 + h * 32;
        size_t gbase = ((size_t)(b * C_ + c0 + cbase)) * (size_t)N_ + m0 + m;
        #pragma unroll 4
        for (int ci = 0; ci < 32; ++ci) {
            float o = Osum[m][cbase + ci];
            size_t ad = gbase + (size_t)ci * N_;
            out[ad] = osc * o + x[ad];
        }
    }
}

extern "C" void kernel_launch(void* const* d_in, const int* in_sizes, int n_in,
                              void* d_out, int out_size, void* d_ws, size_t ws_size,
                              hipStream_t stream) {
    const float* x     = (const float*)d_in[0];
    const float* Wq    = (const float*)d_in[1];
    const float* bq    = (const float*)d_in[2];
    const float* Wk    = (const float*)d_in[3];
    const float* bk    = (const float*)d_in[4];
    const float* Wv    = (const float*)d_in[5];
    const float* bv    = (const float*)d_in[6];
    const float* gamma = (const float*)d_in[7];
    float* out = (float*)d_out;

    unsigned short* qb   = (unsigned short*)d_ws;
    unsigned short* kb   = qb + (size_t)B_ * N_ * D_;
    unsigned short* vb   = kb + (size_t)B_ * N_ * D_;
    unsigned short* Wqkb = vb + (size_t)B_ * C_ * N_;
    unsigned short* Wvb  = Wqkb + 64 * C_;

    prep<<<256, 256, 0, stream>>>(Wq, Wk, Wv, Wqkb, Wvb);
    qkv<<<dim3(128, 4), 256, 0, stream>>>(x, Wqkb, Wvb, bq, bk, bv, qb, kb, vb);
    attn<<<dim3(512), 256, 0, stream>>>(qb, kb, vb, x, gamma, out);
}

// Round 3
// 220.808 us; speedup vs baseline: 1.1308x; 1.1308x over previous
//
#include <hip/hip_runtime.h>

#define B_  4
#define N_  4096   // H*W
#define C_  256
#define D_  32

typedef __attribute__((ext_vector_type(8))) short bf8;   // 8 bf16 (4 VGPRs)
typedef __attribute__((ext_vector_type(4))) float f4;    // MFMA C/D frag

__device__ __forceinline__ unsigned short bft(float f) {
    unsigned u = __builtin_bit_cast(unsigned, f);
    return (unsigned short)((u + 0x8000u) >> 16);
}
// pack two floats to bf16x2 (a->low, b->high), round-half-up, 3 VALU ops
__device__ __forceinline__ unsigned pk2(float a, float b) {
    unsigned ua = __builtin_bit_cast(unsigned, a) + 0x8000u;
    unsigned ub = __builtin_bit_cast(unsigned, b) + 0x8000u;
    return __builtin_amdgcn_perm(ub, ua, 0x07060302u);  // bytes {b3,b2,a3,a2}
}

// ---------------------------------------------------------------------------
// prep: weights -> bf16. Wqkb[64][256] = Wq rows 0-31, Wk rows 32-63.
// ---------------------------------------------------------------------------
__global__ __launch_bounds__(256) void prep(
    const float* __restrict__ Wq, const float* __restrict__ Wk,
    const float* __restrict__ Wv,
    unsigned short* __restrict__ Wqkb, unsigned short* __restrict__ Wvb)
{
    int i = blockIdx.x * 256 + threadIdx.x;
    if (i < 8192)       Wqkb[i] = bft(Wq[i]);
    else if (i < 16384) Wqkb[i] = bft(Wk[i - 8192]);
    Wvb[i] = bft(Wv[i]);
}

// ---------------------------------------------------------------------------
// qkv: MFMA projections, coalesced staging. grid(128,4), 256 thr.
// q is pre-scaled by log2(e) so attn can use raw v_exp_f32 (2^x).
// Outputs: qb,kb [B][N][32] bf16 ; vb [B][C][N] bf16.
// ---------------------------------------------------------------------------
__global__ __launch_bounds__(256) void qkv(
    const float* __restrict__ x,
    const unsigned short* __restrict__ Wqkb, const unsigned short* __restrict__ Wvb,
    const float* __restrict__ bq, const float* __restrict__ bk,
    const float* __restrict__ bv,
    unsigned short* __restrict__ qb, unsigned short* __restrict__ kb,
    unsigned short* __restrict__ vb)
{
    const int b = blockIdx.y, n0 = blockIdx.x * 32;
    const int t = threadIdx.x;
    const int lane = t & 63, w = t >> 6, c15 = lane & 15, g = lane >> 4;

    __shared__ __align__(16) unsigned short xs[32][264];

    // coalesced stage + transpose: 8 lanes cover one 128-B row segment
    {
        const int r = t >> 3, cg = t & 7;
        #pragma unroll
        for (int it = 0; it < 8; ++it) {
            int c = r + 32 * it;
            float4 v = *(const float4*)(x + ((size_t)(b * C_ + c)) * N_ + n0 + cg * 4);
            xs[cg * 4 + 0][c] = bft(v.x);
            xs[cg * 4 + 1][c] = bft(v.y);
            xs[cg * 4 + 2][c] = bft(v.z);
            xs[cg * 4 + 3][c] = bft(v.w);
        }
    }
    __syncthreads();

    f4 qkacc[2]; f4 vacc[2][4];
    const f4 fz = {0.f, 0.f, 0.f, 0.f};
    qkacc[0] = fz; qkacc[1] = fz;
    #pragma unroll
    for (int nt = 0; nt < 2; ++nt)
        #pragma unroll
        for (int ct = 0; ct < 4; ++ct) vacc[nt][ct] = fz;

    const unsigned short* wqk = Wqkb + (w * 16 + c15) * C_ + g * 8;
    const unsigned short* wv0 = Wvb + (w * 64 + c15) * C_ + g * 8;
    const unsigned short* xsp = &xs[c15][g * 8];

    #pragma unroll
    for (int ks = 0; ks < 8; ++ks) {
        bf8 xf0 = *(const bf8*)(xsp + ks * 32);
        bf8 xf1 = *(const bf8*)(xsp + 16 * 264 + ks * 32);
        bf8 af  = *(const bf8*)(wqk + ks * 32);
        qkacc[0] = __builtin_amdgcn_mfma_f32_16x16x32_bf16(af, xf0, qkacc[0], 0, 0, 0);
        qkacc[1] = __builtin_amdgcn_mfma_f32_16x16x32_bf16(af, xf1, qkacc[1], 0, 0, 0);
        #pragma unroll
        for (int ct = 0; ct < 4; ++ct) {
            bf8 bfv = *(const bf8*)(wv0 + ct * 16 * C_ + ks * 32);
            vacc[0][ct] = __builtin_amdgcn_mfma_f32_16x16x32_bf16(xf0, bfv, vacc[0][ct], 0, 0, 0);
            vacc[1][ct] = __builtin_amdgcn_mfma_f32_16x16x32_bf16(xf1, bfv, vacc[1][ct], 0, 0, 0);
        }
    }

    // epilogue q/k (q scaled by log2e for exp2-softmax)
    {
        float4 bias = (w < 2) ? *(const float4*)(bq + (w & 1) * 16 + 4 * g)
                              : *(const float4*)(bk + (w & 1) * 16 + 4 * g);
        float sc = (w < 2) ? 1.44269504f : 1.0f;
        unsigned short* base = (w < 2) ? qb : kb;
        int d0 = (w & 1) * 16 + 4 * g;
        #pragma unroll
        for (int nt = 0; nt < 2; ++nt) {
            int n = n0 + nt * 16 + c15;
            f4 a = qkacc[nt];
            uint2 pk;
            pk.x = pk2((a.x + bias.x) * sc, (a.y + bias.y) * sc);
            pk.y = pk2((a.z + bias.z) * sc, (a.w + bias.w) * sc);
            *(uint2*)(base + ((size_t)(b * N_ + n)) * D_ + d0) = pk;
        }
    }
    // epilogue v
    #pragma unroll
    for (int ct = 0; ct < 4; ++ct) {
        int cout = w * 64 + ct * 16 + c15;
        float bvv = bv[cout];
        #pragma unroll
        for (int nt = 0; nt < 2; ++nt) {
            f4 a = vacc[nt][ct];
            uint2 pk;
            pk.x = pk2(a.x + bvv, a.y + bvv);
            pk.y = pk2(a.z + bvv, a.w + bvv);
            *(uint2*)(vb + ((size_t)(b * C_ + cout)) * (size_t)N_ + n0 + nt * 16 + 4 * g) = pk;
        }
    }
}

// ---------------------------------------------------------------------------
// attn v4: v2 skeleton (LDS P + light barrier + 2 blocks/CU) with P computed
// ONCE: block = 32 m-rows x FULL C=256, 4 waves, grid 512 (128 mb x 4 b) =
// 2 blocks/CU. Per iter (KT=128):
//   produce: wave w owns n-range w*32 -> 4 QK MFMA, exp2, pack, swizzled
//            P-write (XOR byte ^= (row&7)<<4 -> reads AND writes at LDS BW
//            floor, zero conflicts).
//   consume: wave w owns c-range w*64; reads full 8KB P once (A-frags reused
//            over 4 c-frags), owns ALL of k -> no cross-wave O-combine, no
//            atomics; epilogue is direct coalesced float4 stores.
// V L2 traffic doubles vs v2 (1 GB) but is XCD-pinned (bid&3=b -> each XCD
// sees one b: V_b 2MB fits 4MB L2) and prefetched a full phase ahead.
// ---------------------------------------------------------------------------
__global__ __launch_bounds__(256, 2) void attn(
    const unsigned short* __restrict__ qb, const unsigned short* __restrict__ kb,
    const unsigned short* __restrict__ vb, const float* __restrict__ x,
    const float* __restrict__ gamma, float* __restrict__ out)
{
    const int bid = blockIdx.x;
    const int b = bid & 3, m0 = (bid >> 2) * 32;
    const int t = threadIdx.x;
    const int lane = t & 63, w = t >> 6, c15 = lane & 15, g = lane >> 4;
    const int sw = (c15 & 7) << 4;          // LDS XOR swizzle (byte bits 4-6)

    __shared__ __align__(16) unsigned short Ps[2][32 * 128]; // [m][n] 256-B rows, swizzled
    __shared__ float l_s[4][32];

    const f4 fz = {0.f, 0.f, 0.f, 0.f};

    // Q frags (B-operand): lane c15 = m-col, g*8 = d-chunk. Hoisted.
    bf8 qf[2];
    #pragma unroll
    for (int mt = 0; mt < 2; ++mt)
        qf[mt] = *(const bf8*)(qb + ((size_t)(b * N_ + m0 + mt * 16 + c15)) * D_ + g * 8);

    // K frags (A-operand) for n = w*32 + nf*16 + c15; register double-buffer.
    bf8 kfc[2], kfn[2];
    #pragma unroll
    for (int nf = 0; nf < 2; ++nf)
        kfc[nf] = *(const bf8*)(kb + ((size_t)(b * N_ + w * 32 + nf * 16 + c15)) * D_ + g * 8);

    f4 acc[2][4];                            // [m-frag][c-frag], c-base w*64
    #pragma unroll
    for (int mt = 0; mt < 2; ++mt)
        #pragma unroll
        for (int ct = 0; ct < 4; ++ct) acc[mt][ct] = fz;
    float lr[2] = {0.f, 0.f};

    const unsigned short* vB = vb + ((size_t)(b * C_ + w * 64)) * (size_t)N_;

    for (int j0 = 0; j0 < N_; j0 += 128) {
        char* pb = (char*)Ps[(j0 >> 7) & 1];
        // V prefetch for this iter's consume (in flight across the barrier):
        // 16 frags = this wave's 64-c x 128-k tile.
        bf8 vf[4][4];
        #pragma unroll
        for (int ki = 0; ki < 4; ++ki)
            #pragma unroll
            for (int ct = 0; ct < 4; ++ct)
                vf[ki][ct] = *(const bf8*)(vB + (size_t)(ct * 16 + c15) * N_
                                           + j0 + ki * 32 + g * 8);
        // next-iter K prefetch
        if (j0 + 128 < N_) {
            #pragma unroll
            for (int nf = 0; nf < 2; ++nf)
                kfn[nf] = *(const bf8*)(kb + ((size_t)(b * N_ + j0 + 128 + w * 32 + nf * 16 + c15)) * D_ + g * 8);
        }
        // produce S^T = K.Q^T (4 MFMA), exp2, pack, swizzled P write
        #pragma unroll
        for (int mt = 0; mt < 2; ++mt)
            #pragma unroll
            for (int nf = 0; nf < 2; ++nf) {
                f4 s = __builtin_amdgcn_mfma_f32_16x16x32_bf16(kfc[nf], qf[mt], fz, 0, 0, 0);
                float p0 = __builtin_amdgcn_exp2f(s.x);
                float p1 = __builtin_amdgcn_exp2f(s.y);
                float p2 = __builtin_amdgcn_exp2f(s.z);
                float p3 = __builtin_amdgcn_exp2f(s.w);
                lr[mt] += (p0 + p1) + (p2 + p3);
                uint2 pk; pk.x = pk2(p0, p1); pk.y = pk2(p2, p3);
                *(uint2*)(pb + (mt * 16 + c15) * 256 + ((w * 64 + nf * 32 + 8 * g) ^ sw)) = pk;
            }
        kfc[0] = kfn[0]; kfc[1] = kfn[1];
        // light barrier: drain LDS ops only; global loads stay in flight
        asm volatile("s_waitcnt lgkmcnt(0)\n\ts_barrier" ::: "memory");
        // consume: O += P.V^T; this wave owns c-range w*64, all m, all k
        #pragma unroll
        for (int ki = 0; ki < 4; ++ki) {
            bf8 pf[2];
            #pragma unroll
            for (int mt = 0; mt < 2; ++mt)
                pf[mt] = *(const bf8*)(pb + (mt * 16 + c15) * 256 + ((ki * 64 + 16 * g) ^ sw));
            #pragma unroll
            for (int mt = 0; mt < 2; ++mt)
                #pragma unroll
                for (int ct = 0; ct < 4; ++ct)
                    acc[mt][ct] = __builtin_amdgcn_mfma_f32_16x16x32_bf16(pf[mt], vf[ki][ct], acc[mt][ct], 0, 0, 0);
        }
    }

    // l: reduce over g-groups (lanes c15/c15+16/+32/+48), then across waves
    #pragma unroll
    for (int mt = 0; mt < 2; ++mt) {
        lr[mt] += __shfl_xor(lr[mt], 16);
        lr[mt] += __shfl_xor(lr[mt], 32);
    }
    if (lane < 16) { l_s[w][lane] = lr[0]; l_s[w][16 + lane] = lr[1]; }
    __syncthreads();

    // epilogue: wave w writes its m=32 x c=64 tile, coalesced float4 runs
    const float g0 = gamma[0];
    #pragma unroll
    for (int mt = 0; mt < 2; ++mt) {
        float4 a0 = *(const float4*)&l_s[0][mt * 16 + 4 * g];
        float4 a1 = *(const float4*)&l_s[1][mt * 16 + 4 * g];
        float4 a2 = *(const float4*)&l_s[2][mt * 16 + 4 * g];
        float4 a3 = *(const float4*)&l_s[3][mt * 16 + 4 * g];
        float i0 = 1.f / (a0.x + a1.x + a2.x + a3.x);
        float i1 = 1.f / (a0.y + a1.y + a2.y + a3.y);
        float i2 = 1.f / (a0.z + a1.z + a2.z + a3.z);
        float i3 = 1.f / (a0.w + a1.w + a2.w + a3.w);
        #pragma unroll
        for (int ct = 0; ct < 4; ++ct) {
            f4 a = acc[mt][ct];
            int c = w * 64 + ct * 16 + c15;
            size_t base = ((size_t)(b * C_ + c)) * (size_t)N_ + m0 + mt * 16 + 4 * g;
            float4 xv = *(const float4*)(x + base);
            float4 r;
            r.x = g0 * (a.x * i0) + xv.x;
            r.y = g0 * (a.y * i1) + xv.y;
            r.z = g0 * (a.z * i2) + xv.z;
            r.w = g0 * (a.w * i3) + xv.w;
            *(float4*)(out + base) = r;
        }
    }
}

extern "C" void kernel_launch(void* const* d_in, const int* in_sizes, int n_in,
                              void* d_out, int out_size, void* d_ws, size_t ws_size,
                              hipStream_t stream) {
    const float* x     = (const float*)d_in[0];
    const float* Wq    = (const float*)d_in[1];
    const float* bq    = (const float*)d_in[2];
    const float* Wk    = (const float*)d_in[3];
    const float* bk    = (const float*)d_in[4];
    const float* Wv    = (const float*)d_in[5];
    const float* bv    = (const float*)d_in[6];
    const float* gamma = (const float*)d_in[7];
    float* out = (float*)d_out;

    unsigned short* qb   = (unsigned short*)d_ws;
    unsigned short* kb   = qb + (size_t)B_ * N_ * D_;
    unsigned short* vb   = kb + (size_t)B_ * N_ * D_;
    unsigned short* Wqkb = vb + (size_t)B_ * C_ * N_;
    unsigned short* Wvb  = Wqkb + 64 * C_;

    prep<<<256, 256, 0, stream>>>(Wq, Wk, Wv, Wqkb, Wvb);
    qkv<<<dim3(128, 4), 256, 0, stream>>>(x, Wqkb, Wvb, bq, bk, bv, qb, kb, vb);
    attn<<<dim3(512), 256, 0, stream>>>(qb, kb, vb, x, gamma, out);
}

// Round 4
// 167.369 us; speedup vs baseline: 1.4918x; 1.3193x over previous
//
#include <hip/hip_runtime.h>

#define B_  4
#define N_  4096   // H*W
#define C_  256
#define D_  32

typedef __attribute__((ext_vector_type(8))) short bf8;   // 8 bf16 (4 VGPRs)
typedef __attribute__((ext_vector_type(4))) float f4;    // MFMA C/D frag

__device__ __forceinline__ unsigned short bft(float f) {
    unsigned u = __builtin_bit_cast(unsigned, f);
    return (unsigned short)((u + 0x8000u) >> 16);
}
// pack two floats to bf16x2 (a->low, b->high), round-half-up, 3 VALU ops
__device__ __forceinline__ unsigned pk2(float a, float b) {
    unsigned ua = __builtin_bit_cast(unsigned, a) + 0x8000u;
    unsigned ub = __builtin_bit_cast(unsigned, b) + 0x8000u;
    return __builtin_amdgcn_perm(ub, ua, 0x07060302u);  // bytes {b3,b2,a3,a2}
}

// ---------------------------------------------------------------------------
// prep: weights -> bf16. Wqkb[64][256] = Wq rows 0-31, Wk rows 32-63.
// ---------------------------------------------------------------------------
__global__ __launch_bounds__(256) void prep(
    const float* __restrict__ Wq, const float* __restrict__ Wk,
    const float* __restrict__ Wv,
    unsigned short* __restrict__ Wqkb, unsigned short* __restrict__ Wvb)
{
    int i = blockIdx.x * 256 + threadIdx.x;
    if (i < 8192)       Wqkb[i] = bft(Wq[i]);
    else if (i < 16384) Wqkb[i] = bft(Wk[i - 8192]);
    Wvb[i] = bft(Wv[i]);
}

// ---------------------------------------------------------------------------
// qkv: MFMA projections, coalesced staging. grid(128,4), 256 thr.
// q is pre-scaled by log2(e) so attn can use raw v_exp_f32 (2^x).
// Outputs: qb,kb [B][N][32] bf16 ; vb [B][C][N] bf16.
// ---------------------------------------------------------------------------
__global__ __launch_bounds__(256) void qkv(
    const float* __restrict__ x,
    const unsigned short* __restrict__ Wqkb, const unsigned short* __restrict__ Wvb,
    const float* __restrict__ bq, const float* __restrict__ bk,
    const float* __restrict__ bv,
    unsigned short* __restrict__ qb, unsigned short* __restrict__ kb,
    unsigned short* __restrict__ vb)
{
    const int b = blockIdx.y, n0 = blockIdx.x * 32;
    const int t = threadIdx.x;
    const int lane = t & 63, w = t >> 6, c15 = lane & 15, g = lane >> 4;

    __shared__ __align__(16) unsigned short xs[32][264];

    // coalesced stage + transpose: 8 lanes cover one 128-B row segment
    {
        const int r = t >> 3, cg = t & 7;
        #pragma unroll
        for (int it = 0; it < 8; ++it) {
            int c = r + 32 * it;
            float4 v = *(const float4*)(x + ((size_t)(b * C_ + c)) * N_ + n0 + cg * 4);
            xs[cg * 4 + 0][c] = bft(v.x);
            xs[cg * 4 + 1][c] = bft(v.y);
            xs[cg * 4 + 2][c] = bft(v.z);
            xs[cg * 4 + 3][c] = bft(v.w);
        }
    }
    __syncthreads();

    f4 qkacc[2]; f4 vacc[2][4];
    const f4 fz = {0.f, 0.f, 0.f, 0.f};
    qkacc[0] = fz; qkacc[1] = fz;
    #pragma unroll
    for (int nt = 0; nt < 2; ++nt)
        #pragma unroll
        for (int ct = 0; ct < 4; ++ct) vacc[nt][ct] = fz;

    const unsigned short* wqk = Wqkb + (w * 16 + c15) * C_ + g * 8;
    const unsigned short* wv0 = Wvb + (w * 64 + c15) * C_ + g * 8;
    const unsigned short* xsp = &xs[c15][g * 8];

    #pragma unroll
    for (int ks = 0; ks < 8; ++ks) {
        bf8 xf0 = *(const bf8*)(xsp + ks * 32);
        bf8 xf1 = *(const bf8*)(xsp + 16 * 264 + ks * 32);
        bf8 af  = *(const bf8*)(wqk + ks * 32);
        qkacc[0] = __builtin_amdgcn_mfma_f32_16x16x32_bf16(af, xf0, qkacc[0], 0, 0, 0);
        qkacc[1] = __builtin_amdgcn_mfma_f32_16x16x32_bf16(af, xf1, qkacc[1], 0, 0, 0);
        #pragma unroll
        for (int ct = 0; ct < 4; ++ct) {
            bf8 bfv = *(const bf8*)(wv0 + ct * 16 * C_ + ks * 32);
            vacc[0][ct] = __builtin_amdgcn_mfma_f32_16x16x32_bf16(xf0, bfv, vacc[0][ct], 0, 0, 0);
            vacc[1][ct] = __builtin_amdgcn_mfma_f32_16x16x32_bf16(xf1, bfv, vacc[1][ct], 0, 0, 0);
        }
    }

    // epilogue q/k (q scaled by log2e for exp2-softmax)
    {
        float4 bias = (w < 2) ? *(const float4*)(bq + (w & 1) * 16 + 4 * g)
                              : *(const float4*)(bk + (w & 1) * 16 + 4 * g);
        float sc = (w < 2) ? 1.44269504f : 1.0f;
        unsigned short* base = (w < 2) ? qb : kb;
        int d0 = (w & 1) * 16 + 4 * g;
        #pragma unroll
        for (int nt = 0; nt < 2; ++nt) {
            int n = n0 + nt * 16 + c15;
            f4 a = qkacc[nt];
            uint2 pk;
            pk.x = pk2((a.x + bias.x) * sc, (a.y + bias.y) * sc);
            pk.y = pk2((a.z + bias.z) * sc, (a.w + bias.w) * sc);
            *(uint2*)(base + ((size_t)(b * N_ + n)) * D_ + d0) = pk;
        }
    }
    // epilogue v
    #pragma unroll
    for (int ct = 0; ct < 4; ++ct) {
        int cout = w * 64 + ct * 16 + c15;
        float bvv = bv[cout];
        #pragma unroll
        for (int nt = 0; nt < 2; ++nt) {
            f4 a = vacc[nt][ct];
            uint2 pk;
            pk.x = pk2(a.x + bvv, a.y + bvv);
            pk.y = pk2(a.z + bvv, a.w + bvv);
            *(uint2*)(vb + ((size_t)(b * C_ + cout)) * (size_t)N_ + n0 + nt * 16 + 4 * g) = pk;
        }
    }
}

// ---------------------------------------------------------------------------
// attn v5: v2 decomposition (M=64, c-half, 8 waves, grid 512, 2 blocks/CU)
// with the loop ROTATED so each barrier-to-barrier region contains
// consume(i) + produce(i+1) hand-interleaved. This mixes matrix-pipe work
// (consume MFMA) with trans/VALU work (exp2/pack of the NEXT tile) in one
// scheduler region -- v2 ran these as alternating single-pipe bursts, which
// serialized the pipes (sum-of-pipes == wall). One barrier per iter, same
// hazards: region i reads Ps[i&1], writes Ps[(i&1)^1]; the barrier separates
// each buffer's readers from its next writers.
// produce role: wave w owns n-frag w (n = w*16..+15), 4 m-frags.
// consume role: wave (cq=w&3, ksh=w>>2): c-range cq*32 (2 frags), k-half ksh;
// ksh halves combined through LDS at the end.
// ---------------------------------------------------------------------------
__global__ __launch_bounds__(512, 4) void attn(
    const unsigned short* __restrict__ qb, const unsigned short* __restrict__ kb,
    const unsigned short* __restrict__ vb, const float* __restrict__ x,
    const float* __restrict__ gamma, float* __restrict__ out)
{
    const int bid = blockIdx.x;
    const int combo = bid & 7, mb = bid >> 3;
    const int b = combo >> 1, c0 = (combo & 1) * 128, m0 = mb * 64;
    const int t = threadIdx.x;
    const int lane = t & 63, w = t >> 6, c15 = lane & 15, g = lane >> 4;
    const int cq = w & 3, ksh = w >> 2;          // consume role
    const int sw = (c15 & 7) << 4;               // LDS XOR swizzle (byte bits 4-6)

    __shared__ __align__(16) unsigned short Ps[2][64 * 128]; // 256-B rows, swizzled
    __shared__ float l_s[8][64];
    __shared__ __align__(16) float l_tot[64];

    const f4 fz = {0.f, 0.f, 0.f, 0.f};

    bf8 qf[4];
    #pragma unroll
    for (int mi = 0; mi < 4; ++mi)
        qf[mi] = *(const bf8*)(qb + ((size_t)(b * N_ + m0 + mi * 16 + c15)) * D_ + g * 8);

    f4 acc[4][2];
    #pragma unroll
    for (int mt = 0; mt < 4; ++mt)
        #pragma unroll
        for (int ct = 0; ct < 2; ++ct) acc[mt][ct] = fz;
    float lr[4] = {0.f, 0.f, 0.f, 0.f};

    const unsigned short* vbase = vb + ((size_t)(b * C_ + c0 + cq * 32)) * (size_t)N_;
    const unsigned short* kbase = kb + (size_t)b * N_ * D_;

    bf8 kcur;              // K frag for the NEXT tile's produce
    bf8 vcur[2][2], vnxt[2][2];

    // ---- prologue: produce tile 0, stage V(0), K(1) ----
    {
        bf8 kf0 = *(const bf8*)(kbase + (size_t)(w * 16 + c15) * D_ + g * 8);
        #pragma unroll
        for (int ki = 0; ki < 2; ++ki)
            #pragma unroll
            for (int ct = 0; ct < 2; ++ct)
                vcur[ki][ct] = *(const bf8*)(vbase + (size_t)(ct * 16 + c15) * N_
                                             + (ksh * 2 + ki) * 32 + g * 8);
        kcur = *(const bf8*)(kbase + (size_t)(128 + w * 16 + c15) * D_ + g * 8);
        char* pw = (char*)Ps[0];
        #pragma unroll
        for (int mi = 0; mi < 4; ++mi) {
            f4 s = __builtin_amdgcn_mfma_f32_16x16x32_bf16(kf0, qf[mi], fz, 0, 0, 0);
            float p0 = __builtin_amdgcn_exp2f(s.x);
            float p1 = __builtin_amdgcn_exp2f(s.y);
            float p2 = __builtin_amdgcn_exp2f(s.z);
            float p3 = __builtin_amdgcn_exp2f(s.w);
            lr[mi] += (p0 + p1) + (p2 + p3);
            uint2 pk; pk.x = pk2(p0, p1); pk.y = pk2(p2, p3);
            *(uint2*)(pw + (mi * 16 + c15) * 256 + ((w * 32 + 8 * g) ^ sw)) = pk;
        }
        asm volatile("s_waitcnt lgkmcnt(0)\n\ts_barrier" ::: "memory");
    }

    // ---- fused main loop: region i = consume(i) + produce(i+1) ----
    for (int i = 0; i < 31; ++i) {
        const int j0 = i << 7;
        char* pb = (char*)Ps[i & 1];
        char* pw = (char*)Ps[(i & 1) ^ 1];
        // P reads, k-quarter 0 of this wave's half
        bf8 pf0[4];
        #pragma unroll
        for (int mt = 0; mt < 4; ++mt)
            pf0[mt] = *(const bf8*)(pb + (mt * 16 + c15) * 256 + ((ksh * 128 + 16 * g) ^ sw));
        // QK MFMAs for tile i+1 (kcur prefetched last region)
        f4 s[4];
        #pragma unroll
        for (int mi = 0; mi < 4; ++mi)
            s[mi] = __builtin_amdgcn_mfma_f32_16x16x32_bf16(kcur, qf[mi], fz, 0, 0, 0);
        // interleave: per m-frag, 2 consume MFMAs (matrix) + exp/pack/write (trans/VALU/LDS)
        #pragma unroll
        for (int mi = 0; mi < 4; ++mi) {
            acc[mi][0] = __builtin_amdgcn_mfma_f32_16x16x32_bf16(pf0[mi], vcur[0][0], acc[mi][0], 0, 0, 0);
            acc[mi][1] = __builtin_amdgcn_mfma_f32_16x16x32_bf16(pf0[mi], vcur[0][1], acc[mi][1], 0, 0, 0);
            float p0 = __builtin_amdgcn_exp2f(s[mi].x);
            float p1 = __builtin_amdgcn_exp2f(s[mi].y);
            float p2 = __builtin_amdgcn_exp2f(s[mi].z);
            float p3 = __builtin_amdgcn_exp2f(s[mi].w);
            lr[mi] += (p0 + p1) + (p2 + p3);
            uint2 pk; pk.x = pk2(p0, p1); pk.y = pk2(p2, p3);
            *(uint2*)(pw + (mi * 16 + c15) * 256 + ((w * 32 + 8 * g) ^ sw)) = pk;
        }
        // V loads tile i+1, K load tile i+2 (clamped) -- ~600+ cyc before use
        {
            const int j1 = j0 + 128;
            #pragma unroll
            for (int ki = 0; ki < 2; ++ki)
                #pragma unroll
                for (int ct = 0; ct < 2; ++ct)
                    vnxt[ki][ct] = *(const bf8*)(vbase + (size_t)(ct * 16 + c15) * N_
                                                 + j1 + (ksh * 2 + ki) * 32 + g * 8);
            const int j2 = (i < 30) ? j0 + 256 : j0 + 128;
            kcur = *(const bf8*)(kbase + (size_t)(j2 + w * 16 + c15) * D_ + g * 8);
        }
        // P reads + consume MFMAs, k-quarter 1
        bf8 pf1[4];
        #pragma unroll
        for (int mt = 0; mt < 4; ++mt)
            pf1[mt] = *(const bf8*)(pb + (mt * 16 + c15) * 256 + ((ksh * 128 + 64 + 16 * g) ^ sw));
        #pragma unroll
        for (int mt = 0; mt < 4; ++mt)
            #pragma unroll
            for (int ct = 0; ct < 2; ++ct)
                acc[mt][ct] = __builtin_amdgcn_mfma_f32_16x16x32_bf16(pf1[mt], vcur[1][ct], acc[mt][ct], 0, 0, 0);
        #pragma unroll
        for (int ki = 0; ki < 2; ++ki)
            #pragma unroll
            for (int ct = 0; ct < 2; ++ct)
                vcur[ki][ct] = vnxt[ki][ct];
        asm volatile("s_waitcnt lgkmcnt(0)\n\ts_barrier" ::: "memory");
    }

    // ---- final consume: tile 31 (written by region 30 into Ps[1]) ----
    {
        char* pb = (char*)Ps[1];
        #pragma unroll
        for (int ki = 0; ki < 2; ++ki) {
            bf8 pf[4];
            #pragma unroll
            for (int mt = 0; mt < 4; ++mt)
                pf[mt] = *(const bf8*)(pb + (mt * 16 + c15) * 256 + ((ksh * 128 + ki * 64 + 16 * g) ^ sw));
            #pragma unroll
            for (int mt = 0; mt < 4; ++mt)
                #pragma unroll
                for (int ct = 0; ct < 2; ++ct)
                    acc[mt][ct] = __builtin_amdgcn_mfma_f32_16x16x32_bf16(pf[mt], vcur[ki][ct], acc[mt][ct], 0, 0, 0);
        }
    }

    // l: reduce over g-groups, one 16-col partial per wave -> l_s
    #pragma unroll
    for (int mi = 0; mi < 4; ++mi) {
        lr[mi] += __shfl_xor(lr[mi], 16);
        lr[mi] += __shfl_xor(lr[mi], 32);
    }
    if (lane < 16) {
        #pragma unroll
        for (int mi = 0; mi < 4; ++mi) l_s[w][mi * 16 + lane] = lr[mi];
    }
    __syncthreads();   // all consume reads of Ps done before acc dump reuses it

    float* accs = (float*)Ps;  // 32 KB reuse for ksh-combine
    if (ksh == 1) {
        #pragma unroll
        for (int mt = 0; mt < 4; ++mt)
            #pragma unroll
            for (int ct = 0; ct < 2; ++ct)
                *(f4*)&accs[(((cq * 8 + mt * 2 + ct) * 64) + lane) * 4] = acc[mt][ct];
    }
    if (w == 0) {
        float sacc = 0.f;
        #pragma unroll
        for (int ww = 0; ww < 8; ++ww) sacc += l_s[ww][lane];
        l_tot[lane] = sacc;
    }
    __syncthreads();
    if (ksh == 0) {
        const float g0 = gamma[0];
        #pragma unroll
        for (int mt = 0; mt < 4; ++mt) {
            float4 lv = *(const float4*)&l_tot[mt * 16 + 4 * g];
            float i0 = 1.f / lv.x, i1 = 1.f / lv.y, i2 = 1.f / lv.z, i3 = 1.f / lv.w;
            #pragma unroll
            for (int ct = 0; ct < 2; ++ct) {
                f4 o = *(const f4*)&accs[(((cq * 8 + mt * 2 + ct) * 64) + lane) * 4];
                f4 a = acc[mt][ct];
                int c = c0 + cq * 32 + ct * 16 + c15;
                size_t base = ((size_t)(b * C_ + c)) * (size_t)N_ + m0 + mt * 16 + 4 * g;
                float4 xv = *(const float4*)(x + base);
                float4 r;
                r.x = g0 * ((a.x + o.x) * i0) + xv.x;
                r.y = g0 * ((a.y + o.y) * i1) + xv.y;
                r.z = g0 * ((a.z + o.z) * i2) + xv.z;
                r.w = g0 * ((a.w + o.w) * i3) + xv.w;
                *(float4*)(out + base) = r;
            }
        }
    }
}

extern "C" void kernel_launch(void* const* d_in, const int* in_sizes, int n_in,
                              void* d_out, int out_size, void* d_ws, size_t ws_size,
                              hipStream_t stream) {
    const float* x     = (const float*)d_in[0];
    const float* Wq    = (const float*)d_in[1];
    const float* bq    = (const float*)d_in[2];
    const float* Wk    = (const float*)d_in[3];
    const float* bk    = (const float*)d_in[4];
    const float* Wv    = (const float*)d_in[5];
    const float* bv    = (const float*)d_in[6];
    const float* gamma = (const float*)d_in[7];
    float* out = (float*)d_out;

    unsigned short* qb   = (unsigned short*)d_ws;
    unsigned short* kb   = qb + (size_t)B_ * N_ * D_;
    unsigned short* vb   = kb + (size_t)B_ * N_ * D_;
    unsigned short* Wqkb = vb + (size_t)B_ * C_ * N_;
    unsigned short* Wvb  = Wqkb + 64 * C_;

    prep<<<256, 256, 0, stream>>>(Wq, Wk, Wv, Wqkb, Wvb);
    qkv<<<dim3(128, 4), 256, 0, stream>>>(x, Wqkb, Wvb, bq, bk, bv, qb, kb, vb);
    attn<<<dim3(512), 512, 0, stream>>>(qb, kb, vb, x, gamma, out);
}